// Round 7
// baseline (21653.006 us; speedup 1.0000x reference)
//
#include <hip/hip_runtime.h>

#define S_LEN 16384
#define BATCH 128
#define HID   128
#define CHUNK 64
#define NCHUNK (S_LEN / CHUNK)

typedef float f2 __attribute__((ext_vector_type(2)));

// tanh(z) = (e^{2z}-1)/(e^{2z}+1), e^{2z} = exp2(2*log2(e)*z).
// Clamp |z|<=9: tanh(9) = 1 - 2.7e-8 (< fp32 resolution of 1.0).
__device__ __forceinline__ float fast_tanh(float z) {
    z = fminf(fmaxf(z, -9.0f), 9.0f);
    float e = __builtin_amdgcn_exp2f(z * 2.8853900817779268f); // 2*log2(e)
    return (e - 1.0f) * __builtin_amdgcn_rcpf(e + 1.0f);
}

#define REP32(M) M(0) M(1) M(2) M(3) M(4) M(5) M(6) M(7) \
                 M(8) M(9) M(10) M(11) M(12) M(13) M(14) M(15) \
                 M(16) M(17) M(18) M(19) M(20) M(21) M(22) M(23) \
                 M(24) M(25) M(26) M(27) M(28) M(29) M(30) M(31)

// ONE WAVE per chain (128 blocks x 64 threads): zero s_barriers, one LDS
// round-trip per step (the h1 exchange). Lane l owns units jA=l, jB=l+64
// with FULL K=128. The 256 weights live in the AGPR half of gfx950's
// unified 512-reg file ("+a" pins): arch-VGPR pressure stays ~60, so the
// round-5 scratch spill (256 VGPR cap blown, WRITE_SIZE 83MB) cannot
// recur. CDNA2+ VALU reads AGPRs directly as operands.
__global__ __launch_bounds__(64, 1) void ode_scan_kernel(
    const float* __restrict__ x,
    const float* __restrict__ W1, const float* __restrict__ b1,
    const float* __restrict__ W2, const float* __restrict__ b2,
    const float* __restrict__ W3, const float* __restrict__ b3,
    float* __restrict__ out)
{
    const int l  = threadIdx.x;      // lane
    const int bb = blockIdx.x;       // batch chain index
    const int jA = l;                // first owned hidden unit
    const int jB = l + 64;           // second owned hidden unit

    __shared__ __align__(16) float lds_h[HID];
    __shared__ float lds_x[2][CHUNK];

    const float c1A = W1[jA],       c1B = W1[jB];
    const float w1A = W1[HID + jA], w1B = W1[HID + jB];
    const float b1A = b1[jA],       b1B = b1[jB];
    const float b2A = b2[jA],       b2B = b2[jB];
    const float w3A = W3[jA],       w3B = W3[jB];
    const float b3s = b3[0];

    // 256 weights (2 units x K=128) as 128 named f2 pairs, pinned in AGPRs.
#define DECLW(r) \
    f2 wa_##r##_0 = { W2[(4*(r)+0)*HID + jA], W2[(4*(r)+1)*HID + jA] }; \
    f2 wa_##r##_1 = { W2[(4*(r)+2)*HID + jA], W2[(4*(r)+3)*HID + jA] }; \
    f2 wb_##r##_0 = { W2[(4*(r)+0)*HID + jB], W2[(4*(r)+1)*HID + jB] }; \
    f2 wb_##r##_1 = { W2[(4*(r)+2)*HID + jB], W2[(4*(r)+3)*HID + jB] }; \
    asm volatile("" : "+a"(wa_##r##_0), "+a"(wa_##r##_1), \
                      "+a"(wb_##r##_0), "+a"(wb_##r##_1));
    REP32(DECLW)

    // Preload x chunk 0: lds_x[0][t] = x[t][bb].
    lds_x[0][l] = x[l * BATCH + bb];
    __syncthreads();

    float y    = 0.0f;
    float ycap = 0.0f;
    float xc   = lds_x[0][0];
    // Hoisted y-independent parts of layer 1 (computed one step ahead).
    float axA  = fmaf(w1A, xc, b1A);
    float axB  = fmaf(w1B, xc, b1B);
    int   cur  = 0;

    const float4* lh4 = (const float4*)lds_h;

    for (int c = 0; c < NCHUNK; ++c) {
        // Refill other buffer with next chunk (dup-load last chunk, unused).
        int nb = (c + 1 < NCHUNK) ? (c + 1) : c;
        float xf = x[(nb * CHUNK + l) * BATCH + bb];
        lds_x[cur ^ 1][l] = xf;

#pragma unroll 1
        for (int s = 0; s < CHUNK; ++s) {
            float xn = (s < CHUNK - 1) ? lds_x[cur][s + 1] : lds_x[cur ^ 1][0];

            // ---- layer 1: two owned units (hoisted x-part, ILP 2) ----
            float h1A = fast_tanh(fmaf(c1A, y, axA));
            float h1B = fast_tanh(fmaf(c1B, y, axB));
            lds_h[jA] = h1A;
            lds_h[jB] = h1B;
            __syncthreads();             // single wave: waitcnt only, no barrier

            // Next step's x-parts (off critical path, hides under matvec).
            float axAn = fmaf(w1A, xn, b1A);
            float axBn = fmaf(w1B, xn, b1B);

            // ---- layer 2: full-K matvec, 128 v_pk_fma_f32, AGPR weights ----
            f2 aA0 = {0.0f, 0.0f}, aA1 = {0.0f, 0.0f};
            f2 aB0 = {0.0f, 0.0f}, aB1 = {0.0f, 0.0f};
#define MAC(r) { \
            float4 h = lh4[r];       /* broadcast ds_read_b128 */ \
            f2 h01 = { h.x, h.y }, h23 = { h.z, h.w }; \
            aA0 = __builtin_elementwise_fma(h01, wa_##r##_0, aA0); \
            aA1 = __builtin_elementwise_fma(h23, wa_##r##_1, aA1); \
            aB0 = __builtin_elementwise_fma(h01, wb_##r##_0, aB0); \
            aB1 = __builtin_elementwise_fma(h23, wb_##r##_1, aB1); }
            REP32(MAC)

            float sA = ((aA0.x + aA0.y) + (aA1.x + aA1.y)) + b2A;
            float sB = ((aB0.x + aB0.y) + (aB1.x + aB1.y)) + b2B;
            float h2A = fast_tanh(sA);
            float h2B = fast_tanh(sB);
            float p   = fmaf(h2A, w3A, h2B * w3B);

            // ---- layer 3: 64-lane DPP sum (result in lane 63) ----
            asm volatile(
                "s_nop 1\n\t"
                "v_add_f32 %0, %0, %0 row_shr:1 bound_ctrl:0\n\t"
                "s_nop 1\n\t"
                "v_add_f32 %0, %0, %0 row_shr:2 bound_ctrl:0\n\t"
                "s_nop 1\n\t"
                "v_add_f32 %0, %0, %0 row_shr:4 bank_mask:0xe\n\t"
                "s_nop 1\n\t"
                "v_add_f32 %0, %0, %0 row_shr:8 bank_mask:0xc\n\t"
                "s_nop 1\n\t"
                "v_add_f32 %0, %0, %0 row_bcast:15 row_mask:0xa\n\t"
                "s_nop 1\n\t"
                "v_add_f32 %0, %0, %0 row_bcast:31 row_mask:0xc\n\t"
                : "+v"(p));

            float sv;
            asm volatile(
                "s_nop 1\n\t"
                "v_readlane_b32 %0, %1, 63\n\t"
                "s_nop 1"
                : "=s"(sv) : "v"(p));

            y = y + (sv + b3s);              // y_{n+1}, wave-uniform

            ycap = (l == s) ? y : ycap;      // lane s captures ys[c*64+s]
            xc  = xn;
            axA = axAn;
            axB = axBn;
        }

        out[(c * CHUNK + l) * BATCH + bb] = ycap;   // 64 steps per store
        cur ^= 1;
    }
}

extern "C" void kernel_launch(void* const* d_in, const int* in_sizes, int n_in,
                              void* d_out, int out_size, void* d_ws, size_t ws_size,
                              hipStream_t stream) {
    const float* x  = (const float*)d_in[0];
    const float* W1 = (const float*)d_in[1];
    const float* b1 = (const float*)d_in[2];
    const float* W2 = (const float*)d_in[3];
    const float* b2 = (const float*)d_in[4];
    const float* W3 = (const float*)d_in[5];
    const float* b3 = (const float*)d_in[6];
    float* out = (float*)d_out;

    hipLaunchKernelGGL(ode_scan_kernel, dim3(BATCH), dim3(64), 0, stream,
                       x, W1, b1, W2, b2, W3, b3, out);
}

// Round 9
// 7636.202 us; speedup vs baseline: 2.8356x; 2.8356x over previous
//
#include <hip/hip_runtime.h>

#define S_LEN 16384
#define BATCH 128
#define HID   128
#define NTHR  256
#define CHUNK 256
#define NCHUNK (S_LEN / CHUNK)

typedef float f2 __attribute__((ext_vector_type(2)));

// tanh(z) = (e^{2z}-1)/(e^{2z}+1), e^{2z} = exp2(2*log2(e)*z).
// Clamp |z|<=9: tanh(9) = 1 - 2.7e-8 (< fp32 resolution of 1.0).
__device__ __forceinline__ float fast_tanh(float z) {
    z = fminf(fmaxf(z, -9.0f), 9.0f);
    float e = __builtin_amdgcn_exp2f(z * 2.8853900817779268f); // 2*log2(e)
    return (e - 1.0f) * __builtin_amdgcn_rcpf(e + 1.0f);
}

#define REP8(M) M(0) M(1) M(2) M(3) M(4) M(5) M(6) M(7)

// One block = one chain: 256 threads = 4 waves, 1 wave/SIMD.
// K split ACROSS waves: wave w owns K-rows [32w,32w+32). Lane l owns units
// jA=l, jB=l+64 for that K-quarter: 32 f2 weight pairs = 64 VGPRs, total
// pressure ~115 << 256 cap -> no AGPR parking, no spill (R5/6/7 lesson).
// Weights are consumed ONLY by inline-asm v_pk_fma_f32 with "v" constraints
// (VOP3P can't read AGPRs - R8 lesson - so every use anchors VGPR class).
// Wave w also computes layer-1 h1 for ITS OWN K-rows -> h1 exchange is
// wave-internal (in-order DS, no barrier). The single barrier per step is
// the cross-wave partial exchange (parity double-buffered). All 4 waves
// then redundantly finish layers 2-3 -> bit-identical y everywhere.
__global__ __launch_bounds__(NTHR, 1) void ode_scan_kernel(
    const float* __restrict__ x,
    const float* __restrict__ W1, const float* __restrict__ b1,
    const float* __restrict__ W2, const float* __restrict__ b2,
    const float* __restrict__ W3, const float* __restrict__ b3,
    float* __restrict__ out)
{
    const int tid  = threadIdx.x;
    const int bb   = blockIdx.x;     // batch chain index
    const int l    = tid & 63;       // lane
    const int w    = tid >> 6;       // wave = K-quarter
    const int koff = w << 5;         // first K-row of this wave
    const int jA   = l;              // owned units
    const int jB   = l + 64;
    const int row  = koff + (l & 31);// layer-1 row (lanes 32.. duplicate)

    __shared__ __align__(16) float lds_h[4][32];    // per-wave h1 quarter
    __shared__ __align__(16) f2    lds_p[2][4][64]; // [par][wave][lane]={pA,pB}
    __shared__ float lds_x[2][CHUNK];

    // layer-1 constants for this lane's K-row
    const float c1  = W1[row];          // y coefficient (row 0 of W1)
    const float w1x = W1[HID + row];    // x coefficient (row 1 of W1)
    const float b1r = b1[row];
    // layer-2/3 constants for the two owned units
    const float b2A = b2[jA], b2B = b2[jB];
    const float w3A = W3[jA], w3B = W3[jB];
    const float b3s = b3[0];

    // 64 weights: W2[koff+4r+t][jA/jB] as 32 named f2 pairs.
#define DECLW(r) \
    f2 wA##r##a = { W2[(koff+4*(r)+0)*HID + jA], W2[(koff+4*(r)+1)*HID + jA] }; \
    f2 wA##r##b = { W2[(koff+4*(r)+2)*HID + jA], W2[(koff+4*(r)+3)*HID + jA] }; \
    f2 wB##r##a = { W2[(koff+4*(r)+0)*HID + jB], W2[(koff+4*(r)+1)*HID + jB] }; \
    f2 wB##r##b = { W2[(koff+4*(r)+2)*HID + jB], W2[(koff+4*(r)+3)*HID + jB] };
    REP8(DECLW)

    // Preload x chunk 0: lds_x[0][t] = x[t][bb].
    lds_x[0][tid] = x[tid * BATCH + bb];
    __syncthreads();

    float y    = 0.0f;
    float ycap = 0.0f;
    float ax   = fmaf(w1x, lds_x[0][0], b1r);  // hoisted y-independent part
    int   cur  = 0;

    const float4* lh4 = (const float4*)lds_h[w];   // own wave's 32-float quarter

    for (int c = 0; c < NCHUNK; ++c) {
        // Refill other x buffer with next chunk (dup-load last, unused).
        int nb = (c + 1 < NCHUNK) ? (c + 1) : c;
        float xf = x[(nb * CHUNK + tid) * BATCH + bb];
        lds_x[cur ^ 1][tid] = xf;

#pragma unroll 1
        for (int s = 0; s < CHUNK; ++s) {
            float xn  = (s < CHUNK - 1) ? lds_x[cur][s + 1] : lds_x[cur ^ 1][0];

            // ---- layer 1 for this wave's own K-row (no barrier needed) ----
            float h1 = fast_tanh(fmaf(c1, y, ax));
            lds_h[w][l & 31] = h1;     // dual-lane same-addr same-value: ok

            float axn = fmaf(w1x, xn, b1r);   // next step, off critical path

            // ---- layer 2 (quarter-K x 2 units): 32 v_pk_fma_f32 ----
            f2 aA0 = {0.f,0.f}, aA1 = {0.f,0.f};
            f2 aB0 = {0.f,0.f}, aB1 = {0.f,0.f};
#define MAC(r) { float4 h = lh4[r];  /* broadcast ds_read_b128 */ \
            f2 h01 = { h.x, h.y }, h23 = { h.z, h.w }; \
            asm("v_pk_fma_f32 %0, %1, %2, %0" : "+v"(aA0) : "v"(wA##r##a), "v"(h01)); \
            asm("v_pk_fma_f32 %0, %1, %2, %0" : "+v"(aA1) : "v"(wA##r##b), "v"(h23)); \
            asm("v_pk_fma_f32 %0, %1, %2, %0" : "+v"(aB0) : "v"(wB##r##a), "v"(h01)); \
            asm("v_pk_fma_f32 %0, %1, %2, %0" : "+v"(aB1) : "v"(wB##r##b), "v"(h23)); }
            REP8(MAC)

            f2 tA = aA0 + aA1;               // v_pk_add_f32
            f2 tB = aB0 + aB1;
            f2 pv;                           // {partial_jA, partial_jB}
            pv.x = tA.x + tA.y;
            pv.y = tB.x + tB.y;

            // ---- publish partials; the ONE barrier per step ----
            const int buf = s & 1;           // parity double-buffer: WAR-safe
            lds_p[buf][w][l] = pv;           // ds_write_b64
            __syncthreads();

            // ---- finish: all 4 waves redundantly, bit-identical ----
            f2 r0 = lds_p[buf][0][l];
            f2 r1 = lds_p[buf][1][l];
            f2 r2 = lds_p[buf][2][l];
            f2 r3 = lds_p[buf][3][l];
            f2 q  = (r0 + r1) + (r2 + r3);   // {sum_jA, sum_jB} over K=128
            float h2A = fast_tanh(q.x + b2A);
            float h2B = fast_tanh(q.y + b2B);
            float p   = fmaf(h2A, w3A, h2B * w3B);

            // 64-lane DPP sum (covers all 128 units) -> lane 63
            asm volatile(
                "s_nop 1\n\t"
                "v_add_f32 %0, %0, %0 row_shr:1 bound_ctrl:0\n\t"
                "s_nop 1\n\t"
                "v_add_f32 %0, %0, %0 row_shr:2 bound_ctrl:0\n\t"
                "s_nop 1\n\t"
                "v_add_f32 %0, %0, %0 row_shr:4 bank_mask:0xe\n\t"
                "s_nop 1\n\t"
                "v_add_f32 %0, %0, %0 row_shr:8 bank_mask:0xc\n\t"
                "s_nop 1\n\t"
                "v_add_f32 %0, %0, %0 row_bcast:15 row_mask:0xa\n\t"
                "s_nop 1\n\t"
                "v_add_f32 %0, %0, %0 row_bcast:31 row_mask:0xc\n\t"
                : "+v"(p));
            float sv;
            asm volatile(
                "s_nop 1\n\t"
                "v_readlane_b32 %0, %1, 63\n\t"
                "s_nop 1"
                : "=s"(sv) : "v"(p));

            y = y + (sv + b3s);              // y_{n+1}, identical in all waves
            ycap = (tid == s) ? y : ycap;    // thread s captures ys[c*256+s]
            ax = axn;
        }
        out[(c * CHUNK + tid) * BATCH + bb] = ycap;   // 256 steps per store
        cur ^= 1;
    }
}

extern "C" void kernel_launch(void* const* d_in, const int* in_sizes, int n_in,
                              void* d_out, int out_size, void* d_ws, size_t ws_size,
                              hipStream_t stream) {
    const float* x  = (const float*)d_in[0];
    const float* W1 = (const float*)d_in[1];
    const float* b1 = (const float*)d_in[2];
    const float* W2 = (const float*)d_in[3];
    const float* b2 = (const float*)d_in[4];
    const float* W3 = (const float*)d_in[5];
    const float* b3 = (const float*)d_in[6];
    float* out = (float*)d_out;

    hipLaunchKernelGGL(ode_scan_kernel, dim3(BATCH), dim3(NTHR), 0, stream,
                       x, W1, b1, W2, b2, W3, b3, out);
}

// Round 10
// 6992.728 us; speedup vs baseline: 3.0965x; 1.0920x over previous
//
#include <hip/hip_runtime.h>

#define S_LEN 16384
#define BATCH 128
#define HID   128
#define NTHR  256
#define CHUNK 256
#define NCHUNK (S_LEN / CHUNK)

typedef float f2 __attribute__((ext_vector_type(2)));

// tanh(z) = (e^{2z}-1)/(e^{2z}+1), e^{2z} = exp2(2*log2(e)*z).
// Clamp |z|<=9: tanh(9) = 1 - 2.7e-8 (< fp32 resolution of 1.0).
__device__ __forceinline__ float fast_tanh(float z) {
    z = fminf(fmaxf(z, -9.0f), 9.0f);
    float e = __builtin_amdgcn_exp2f(z * 2.8853900817779268f); // 2*log2(e)
    return (e - 1.0f) * __builtin_amdgcn_rcpf(e + 1.0f);
}

#define REP8(M) M(0) M(1) M(2) M(3) M(4) M(5) M(6) M(7)

// One block = one chain: 256 threads = 4 waves, 1 wave/SIMD.
// K split ACROSS waves: wave w owns K-rows [32w,32w+32). Lane l owns units
// jA=l, jB=l+64 for that K-quarter: 32 f2 weight pairs = 64 VGPRs.
// ROUND-10 CHANGE: amdgpu_waves_per_eu(1,1). Round 9's VGPR_Count=52 proved
// the allocator parked the weights in AGPRs (chasing 8-wave occupancy that
// launch_bounds' MIN doesn't forbid) and re-copied them through
// v_accvgpr_read on every use — ~64 dependent VALU copies on the serial
// critical path per step. Pinning occupancy at 1 wave/EU (which our grid
// gives anyway: 128 blocks x 4 waves on 256 CUs) removes the allocator's
// only incentive to shrink arch-VGPR count; at ~115 live regs there is
// nothing to spill. Everything else is byte-identical to round 9.
__attribute__((amdgpu_waves_per_eu(1, 1)))
__global__ __launch_bounds__(NTHR, 1) void ode_scan_kernel(
    const float* __restrict__ x,
    const float* __restrict__ W1, const float* __restrict__ b1,
    const float* __restrict__ W2, const float* __restrict__ b2,
    const float* __restrict__ W3, const float* __restrict__ b3,
    float* __restrict__ out)
{
    const int tid  = threadIdx.x;
    const int bb   = blockIdx.x;     // batch chain index
    const int l    = tid & 63;       // lane
    const int w    = tid >> 6;       // wave = K-quarter
    const int koff = w << 5;         // first K-row of this wave
    const int jA   = l;              // owned units
    const int jB   = l + 64;
    const int row  = koff + (l & 31);// layer-1 row (lanes 32.. duplicate)

    __shared__ __align__(16) float lds_h[4][32];    // per-wave h1 quarter
    __shared__ __align__(16) f2    lds_p[2][4][64]; // [par][wave][lane]={pA,pB}
    __shared__ float lds_x[2][CHUNK];

    // layer-1 constants for this lane's K-row
    const float c1  = W1[row];          // y coefficient (row 0 of W1)
    const float w1x = W1[HID + row];    // x coefficient (row 1 of W1)
    const float b1r = b1[row];
    // layer-2/3 constants for the two owned units
    const float b2A = b2[jA], b2B = b2[jB];
    const float w3A = W3[jA], w3B = W3[jB];
    const float b3s = b3[0];

    // 64 weights: W2[koff+4r+t][jA/jB] as 32 named f2 pairs.
#define DECLW(r) \
    f2 wA##r##a = { W2[(koff+4*(r)+0)*HID + jA], W2[(koff+4*(r)+1)*HID + jA] }; \
    f2 wA##r##b = { W2[(koff+4*(r)+2)*HID + jA], W2[(koff+4*(r)+3)*HID + jA] }; \
    f2 wB##r##a = { W2[(koff+4*(r)+0)*HID + jB], W2[(koff+4*(r)+1)*HID + jB] }; \
    f2 wB##r##b = { W2[(koff+4*(r)+2)*HID + jB], W2[(koff+4*(r)+3)*HID + jB] };
    REP8(DECLW)

    // Preload x chunk 0: lds_x[0][t] = x[t][bb].
    lds_x[0][tid] = x[tid * BATCH + bb];
    __syncthreads();

    float y    = 0.0f;
    float ycap = 0.0f;
    float ax   = fmaf(w1x, lds_x[0][0], b1r);  // hoisted y-independent part
    int   cur  = 0;

    const float4* lh4 = (const float4*)lds_h[w];   // own wave's 32-float quarter

    for (int c = 0; c < NCHUNK; ++c) {
        // Refill other x buffer with next chunk (dup-load last, unused).
        int nb = (c + 1 < NCHUNK) ? (c + 1) : c;
        float xf = x[(nb * CHUNK + tid) * BATCH + bb];
        lds_x[cur ^ 1][tid] = xf;

#pragma unroll 1
        for (int s = 0; s < CHUNK; ++s) {
            float xn  = (s < CHUNK - 1) ? lds_x[cur][s + 1] : lds_x[cur ^ 1][0];

            // ---- layer 1 for this wave's own K-row (no barrier needed) ----
            float h1 = fast_tanh(fmaf(c1, y, ax));
            lds_h[w][l & 31] = h1;     // dual-lane same-addr same-value: ok

            float axn = fmaf(w1x, xn, b1r);   // next step, off critical path

            // ---- layer 2 (quarter-K x 2 units): 32 v_pk_fma_f32 ----
            f2 aA0 = {0.f,0.f}, aA1 = {0.f,0.f};
            f2 aB0 = {0.f,0.f}, aB1 = {0.f,0.f};
#define MAC(r) { float4 h = lh4[r];  /* broadcast ds_read_b128 */ \
            f2 h01 = { h.x, h.y }, h23 = { h.z, h.w }; \
            asm("v_pk_fma_f32 %0, %1, %2, %0" : "+v"(aA0) : "v"(wA##r##a), "v"(h01)); \
            asm("v_pk_fma_f32 %0, %1, %2, %0" : "+v"(aA1) : "v"(wA##r##b), "v"(h23)); \
            asm("v_pk_fma_f32 %0, %1, %2, %0" : "+v"(aB0) : "v"(wB##r##a), "v"(h01)); \
            asm("v_pk_fma_f32 %0, %1, %2, %0" : "+v"(aB1) : "v"(wB##r##b), "v"(h23)); }
            REP8(MAC)

            f2 tA = aA0 + aA1;               // v_pk_add_f32
            f2 tB = aB0 + aB1;
            f2 pv;                           // {partial_jA, partial_jB}
            pv.x = tA.x + tA.y;
            pv.y = tB.x + tB.y;

            // ---- publish partials; the ONE barrier per step ----
            const int buf = s & 1;           // parity double-buffer: WAR-safe
            lds_p[buf][w][l] = pv;           // ds_write_b64
            __syncthreads();

            // ---- finish: all 4 waves redundantly, bit-identical ----
            f2 r0 = lds_p[buf][0][l];
            f2 r1 = lds_p[buf][1][l];
            f2 r2 = lds_p[buf][2][l];
            f2 r3 = lds_p[buf][3][l];
            f2 q  = (r0 + r1) + (r2 + r3);   // {sum_jA, sum_jB} over K=128
            float h2A = fast_tanh(q.x + b2A);
            float h2B = fast_tanh(q.y + b2B);
            float p   = fmaf(h2A, w3A, h2B * w3B);

            // 64-lane DPP sum (covers all 128 units) -> lane 63
            asm volatile(
                "s_nop 1\n\t"
                "v_add_f32 %0, %0, %0 row_shr:1 bound_ctrl:0\n\t"
                "s_nop 1\n\t"
                "v_add_f32 %0, %0, %0 row_shr:2 bound_ctrl:0\n\t"
                "s_nop 1\n\t"
                "v_add_f32 %0, %0, %0 row_shr:4 bank_mask:0xe\n\t"
                "s_nop 1\n\t"
                "v_add_f32 %0, %0, %0 row_shr:8 bank_mask:0xc\n\t"
                "s_nop 1\n\t"
                "v_add_f32 %0, %0, %0 row_bcast:15 row_mask:0xa\n\t"
                "s_nop 1\n\t"
                "v_add_f32 %0, %0, %0 row_bcast:31 row_mask:0xc\n\t"
                : "+v"(p));
            float sv;
            asm volatile(
                "s_nop 1\n\t"
                "v_readlane_b32 %0, %1, 63\n\t"
                "s_nop 1"
                : "=s"(sv) : "v"(p));

            y = y + (sv + b3s);              // y_{n+1}, identical in all waves
            ycap = (tid == s) ? y : ycap;    // thread s captures ys[c*256+s]
            ax = axn;
        }
        out[(c * CHUNK + tid) * BATCH + bb] = ycap;   // 256 steps per store
        cur ^= 1;
    }
}

extern "C" void kernel_launch(void* const* d_in, const int* in_sizes, int n_in,
                              void* d_out, int out_size, void* d_ws, size_t ws_size,
                              hipStream_t stream) {
    const float* x  = (const float*)d_in[0];
    const float* W1 = (const float*)d_in[1];
    const float* b1 = (const float*)d_in[2];
    const float* W2 = (const float*)d_in[3];
    const float* b2 = (const float*)d_in[4];
    const float* W3 = (const float*)d_in[5];
    const float* b3 = (const float*)d_in[6];
    float* out = (float*)d_out;

    hipLaunchKernelGGL(ode_scan_kernel, dim3(BATCH), dim3(NTHR), 0, stream,
                       x, W1, b1, W2, b2, W3, b3, out);
}

// Round 11
// 6731.067 us; speedup vs baseline: 3.2169x; 1.0389x over previous
//
#include <hip/hip_runtime.h>

#define S_LEN 16384
#define BATCH 128
#define HID   128
#define NTHR  256
#define CHUNK 256
#define NCHUNK (S_LEN / CHUNK)

typedef float f2 __attribute__((ext_vector_type(2)));

// Clamp-free tanh: tanh(z) = 1 - 2/(e^{2z}+1).
// e^{2z} = exp2(z*2*log2(e)); exp2 -> +inf gives 1-0 = +1, exp2 -> 0 gives
// 1-2 = -1, so saturation is exact without a clamp (2 fewer serial VALU ops).
__device__ __forceinline__ float fast_tanh(float z) {
    float e = __builtin_amdgcn_exp2f(z * 2.8853900817779268f);
    return fmaf(-2.0f, __builtin_amdgcn_rcpf(e + 1.0f), 1.0f);
}

#define REP8(M) M(0) M(1) M(2) M(3) M(4) M(5) M(6) M(7)

// One block = one chain: 256 threads = 4 waves, 1 wave/SIMD.
// K split ACROSS waves: wave w owns K-rows [32w,32w+32). Lane l owns units
// jA=l, jB=l+64 for that K-quarter: 32 f2 weight pairs, arch-VGPR-resident
// (VGPR_Count=132 verified in round 10 with waves_per_eu(1,1)).
// h1 exchange is wave-internal (in-order DS, no barrier); the single
// barrier per step is the cross-wave partial exchange (parity dbuf).
// ROUND-11: serial-path shavers. (a) clamp-free tanh (3 tanh on path);
// (b) carried svb/base: next layer-1 input = fmaf(c1, svb, base) where
// base = c1*y + ax_next is computed OFF-PATH mid-step, so the readlane
// result feeds one fma then tanh — the y update and ycap capture leave
// the critical path; (c) x-prefetch/axn/base moved after the pv publish
// to fill the pre-barrier lgkmcnt-drain window.
__attribute__((amdgpu_waves_per_eu(1, 1)))
__global__ __launch_bounds__(NTHR, 1) void ode_scan_kernel(
    const float* __restrict__ x,
    const float* __restrict__ W1, const float* __restrict__ b1,
    const float* __restrict__ W2, const float* __restrict__ b2,
    const float* __restrict__ W3, const float* __restrict__ b3,
    float* __restrict__ out)
{
    const int tid  = threadIdx.x;
    const int bb   = blockIdx.x;     // batch chain index
    const int l    = tid & 63;       // lane
    const int w    = tid >> 6;       // wave = K-quarter
    const int koff = w << 5;         // first K-row of this wave
    const int jA   = l;              // owned units
    const int jB   = l + 64;
    const int row  = koff + (l & 31);// layer-1 row (lanes 32.. duplicate)

    __shared__ __align__(16) float lds_h[4][32];    // per-wave h1 quarter
    __shared__ __align__(16) f2    lds_p[2][4][64]; // [par][wave][lane]={pA,pB}
    __shared__ float lds_x[2][CHUNK];

    // layer-1 constants for this lane's K-row
    const float c1  = W1[row];          // y coefficient (row 0 of W1)
    const float w1x = W1[HID + row];    // x coefficient (row 1 of W1)
    const float b1r = b1[row];
    // layer-2/3 constants for the two owned units
    const float b2A = b2[jA], b2B = b2[jB];
    const float w3A = W3[jA], w3B = W3[jB];
    const float b3s = b3[0];

    // 64 weights: W2[koff+4r+t][jA/jB] as 32 named f2 pairs.
#define DECLW(r) \
    f2 wA##r##a = { W2[(koff+4*(r)+0)*HID + jA], W2[(koff+4*(r)+1)*HID + jA] }; \
    f2 wA##r##b = { W2[(koff+4*(r)+2)*HID + jA], W2[(koff+4*(r)+3)*HID + jA] }; \
    f2 wB##r##a = { W2[(koff+4*(r)+0)*HID + jB], W2[(koff+4*(r)+1)*HID + jB] }; \
    f2 wB##r##b = { W2[(koff+4*(r)+2)*HID + jB], W2[(koff+4*(r)+3)*HID + jB] };
    REP8(DECLW)

    // Preload x chunk 0: lds_x[0][t] = x[t][bb].
    lds_x[0][tid] = x[tid * BATCH + bb];
    __syncthreads();

    // Carried state: y (pre-update), svb (last step's Δy), base (= c1*y + ax
    // for the CURRENT step), ycap (captured output history).
    float y    = 0.0f;
    float ycap = 0.0f;
    float svb  = 0.0f;
    float base = fmaf(w1x, lds_x[0][0], b1r);  // = ax_0 (y_0 = 0)
    int   cur  = 0;

    const float4* lh4 = (const float4*)lds_h[w];   // own wave's 32-float quarter

    for (int c = 0; c < NCHUNK; ++c) {
        // Refill other x buffer with next chunk (dup-load last, unused).
        int nb = (c + 1 < NCHUNK) ? (c + 1) : c;
        float xf = x[(nb * CHUNK + tid) * BATCH + bb];
        lds_x[cur ^ 1][tid] = xf;

#pragma unroll 1
        for (int s = 0; s < CHUNK; ++s) {
            // ---- layer 1: z = c1*y_n + ax_n = base + c1*svb_{n-1} ----
            float h1 = fast_tanh(fmaf(c1, svb, base));
            lds_h[w][l & 31] = h1;     // wave-internal (in-order DS, no barrier)

            y += svb;                  // y_n (off critical path)

            // ---- layer 2 (quarter-K x 2 units): 32 v_pk_fma_f32 ----
            f2 aA0 = {0.f,0.f}, aA1 = {0.f,0.f};
            f2 aB0 = {0.f,0.f}, aB1 = {0.f,0.f};
#define MAC(r) { float4 h = lh4[r];  /* broadcast ds_read_b128 */ \
            f2 h01 = { h.x, h.y }, h23 = { h.z, h.w }; \
            asm("v_pk_fma_f32 %0, %1, %2, %0" : "+v"(aA0) : "v"(wA##r##a), "v"(h01)); \
            asm("v_pk_fma_f32 %0, %1, %2, %0" : "+v"(aA1) : "v"(wA##r##b), "v"(h23)); \
            asm("v_pk_fma_f32 %0, %1, %2, %0" : "+v"(aB0) : "v"(wB##r##a), "v"(h01)); \
            asm("v_pk_fma_f32 %0, %1, %2, %0" : "+v"(aB1) : "v"(wB##r##b), "v"(h23)); }
            REP8(MAC)

            f2 tA = aA0 + aA1;               // v_pk_add_f32
            f2 tB = aB0 + aB1;
            f2 pv;                           // {partial_jA, partial_jB}
            pv.x = tA.x + tA.y;
            pv.y = tB.x + tB.y;

            // ---- publish partials ASAP ----
            const int buf = s & 1;           // parity double-buffer: WAR-safe
            lds_p[buf][w][l] = pv;           // ds_write_b64

            // ---- off-path work fills the pre-barrier drain window ----
            float xn  = (s < CHUNK - 1) ? lds_x[cur][s + 1] : lds_x[cur ^ 1][0];
            float axn = fmaf(w1x, xn, b1r);  // ax_{n+1}
            base = fmaf(c1, y, axn);         // c1*y_n + ax_{n+1}

            __syncthreads();                 // the ONE barrier per step

            // ---- finish: all 4 waves redundantly, bit-identical ----
            f2 r0 = lds_p[buf][0][l];
            f2 r1 = lds_p[buf][1][l];
            f2 r2 = lds_p[buf][2][l];
            f2 r3 = lds_p[buf][3][l];
            f2 q  = (r0 + r1) + (r2 + r3);   // {sum_jA, sum_jB} over K=128
            float h2A = fast_tanh(q.x + b2A);
            float h2B = fast_tanh(q.y + b2B);
            float p   = fmaf(h2A, w3A, h2B * w3B);

            // 64-lane DPP sum (covers all 128 units) -> lane 63
            asm volatile(
                "s_nop 1\n\t"
                "v_add_f32 %0, %0, %0 row_shr:1 bound_ctrl:0\n\t"
                "s_nop 1\n\t"
                "v_add_f32 %0, %0, %0 row_shr:2 bound_ctrl:0\n\t"
                "s_nop 1\n\t"
                "v_add_f32 %0, %0, %0 row_shr:4 bank_mask:0xe\n\t"
                "s_nop 1\n\t"
                "v_add_f32 %0, %0, %0 row_shr:8 bank_mask:0xc\n\t"
                "s_nop 1\n\t"
                "v_add_f32 %0, %0, %0 row_bcast:15 row_mask:0xa\n\t"
                "s_nop 1\n\t"
                "v_add_f32 %0, %0, %0 row_bcast:31 row_mask:0xc\n\t"
                : "+v"(p));
            float sv;
            asm volatile(
                "s_nop 1\n\t"
                "v_readlane_b32 %0, %1, 63\n\t"
                "s_nop 1"
                : "=s"(sv) : "v"(p));

            svb = sv + b3s;                  // Δy_n; feeds next layer-1 directly
            ycap = (tid == s) ? (y + svb) : ycap;  // y_{n+1} capture (off-path)
        }
        out[(c * CHUNK + tid) * BATCH + bb] = ycap;   // 256 steps per store
        cur ^= 1;
    }
}

extern "C" void kernel_launch(void* const* d_in, const int* in_sizes, int n_in,
                              void* d_out, int out_size, void* d_ws, size_t ws_size,
                              hipStream_t stream) {
    const float* x  = (const float*)d_in[0];
    const float* W1 = (const float*)d_in[1];
    const float* b1 = (const float*)d_in[2];
    const float* W2 = (const float*)d_in[3];
    const float* b2 = (const float*)d_in[4];
    const float* W3 = (const float*)d_in[5];
    const float* b3 = (const float*)d_in[6];
    float* out = (float*)d_out;

    hipLaunchKernelGGL(ode_scan_kernel, dim3(BATCH), dim3(NTHR), 0, stream,
                       x, W1, b1, W2, b2, W3, b3, out);
}

// Round 13
// 5826.417 us; speedup vs baseline: 3.7164x; 1.1553x over previous
//
#include <hip/hip_runtime.h>

#define S_LEN 16384
#define BATCH 128
#define HID   128
#define NTHR  256
#define CHUNK 256
#define NCHUNK (S_LEN / CHUNK)

typedef float f2 __attribute__((ext_vector_type(2)));

// Clamp-free tanh: tanh(z) = 1 - 2/(e^{2z}+1).
__device__ __forceinline__ float fast_tanh(float z) {
    float e = __builtin_amdgcn_exp2f(z * 2.8853900817779268f);
    return fmaf(-2.0f, __builtin_amdgcn_rcpf(e + 1.0f), 1.0f);
}

// Compiler-generated lane broadcast (hazards handled by LLVM, unlike the
// R12 hand-asm which hit the SGPR-write->VALU-read hazard and corrupted).
__device__ __forceinline__ float rdlane(float v, int lane) {
    return __uint_as_float(__builtin_amdgcn_readlane(__float_as_uint(v), lane));
}

// One block = one chain: 256 threads = 4 waves, 1 wave/SIMD.
// K split ACROSS waves: wave w owns K-rows [32w,32w+32). Lane l owns units
// jA=l, jB=l+64 for that K-quarter. Weights now packed PER ROW across the
// two units: w_i = {W2[i][jA], W2[i][jB]} (32 f2 = 64 VGPRs, same budget,
// arch-resident per R10/R11's waves_per_eu(1,1) + VGPR_Count=132 evidence).
// ROUND-13: h1 broadcast via compiler readlane -> SGPR (VALU pipe) instead
// of the LDS round-trip (~150-200 cyc DS latency on the serial path).
// One pk-FMA per row covers both units: acc = fma({h,h}, w_i, acc); the
// cross-wave partial pv = {pA,pB} falls out of the accumulator sum.
// lds_h deleted; pv exchange + single barrier unchanged from R11.
__attribute__((amdgpu_waves_per_eu(1, 1)))
__global__ __launch_bounds__(NTHR, 1) void ode_scan_kernel(
    const float* __restrict__ x,
    const float* __restrict__ W1, const float* __restrict__ b1,
    const float* __restrict__ W2, const float* __restrict__ b2,
    const float* __restrict__ W3, const float* __restrict__ b3,
    float* __restrict__ out)
{
    const int tid  = threadIdx.x;
    const int bb   = blockIdx.x;     // batch chain index
    const int l    = tid & 63;       // lane
    const int w    = tid >> 6;       // wave = K-quarter
    const int koff = w << 5;         // first K-row of this wave
    const int jA   = l;              // owned units
    const int jB   = l + 64;
    const int row  = koff + (l & 31);// layer-1 row (lanes 32.. duplicate)

    __shared__ __align__(16) f2    lds_p[2][4][64]; // [par][wave][lane]={pA,pB}
    __shared__ float lds_x[2][CHUNK];

    // layer-1 constants for this lane's K-row
    const float c1  = W1[row];          // y coefficient (row 0 of W1)
    const float w1x = W1[HID + row];    // x coefficient (row 1 of W1)
    const float b1r = b1[row];
    // layer-2/3 constants for the two owned units
    const float b2A = b2[jA], b2B = b2[jB];
    const float w3A = W3[jA], w3B = W3[jB];
    const float b3s = b3[0];

    // 32 rows x {unitA, unitB}: w##r##_##t = {W2[koff+4r+t][jA], ..[jB]}.
#define REP8(M) M(0) M(1) M(2) M(3) M(4) M(5) M(6) M(7)
#define DECLW(r) \
    f2 w##r##_0 = { W2[(koff+4*(r)+0)*HID + jA], W2[(koff+4*(r)+0)*HID + jB] }; \
    f2 w##r##_1 = { W2[(koff+4*(r)+1)*HID + jA], W2[(koff+4*(r)+1)*HID + jB] }; \
    f2 w##r##_2 = { W2[(koff+4*(r)+2)*HID + jA], W2[(koff+4*(r)+2)*HID + jB] }; \
    f2 w##r##_3 = { W2[(koff+4*(r)+3)*HID + jA], W2[(koff+4*(r)+3)*HID + jB] };
    REP8(DECLW)

    // Preload x chunk 0: lds_x[0][t] = x[t][bb].
    lds_x[0][tid] = x[tid * BATCH + bb];
    __syncthreads();

    // Carried state: y (pre-update), svb (last step's Δy), base (= c1*y + ax
    // for the CURRENT step), ycap (captured output history).
    float y    = 0.0f;
    float ycap = 0.0f;
    float svb  = 0.0f;
    float base = fmaf(w1x, lds_x[0][0], b1r);  // = ax_0 (y_0 = 0)
    int   cur  = 0;

    for (int c = 0; c < NCHUNK; ++c) {
        // Refill other x buffer with next chunk (dup-load last, unused).
        int nb = (c + 1 < NCHUNK) ? (c + 1) : c;
        float xf = x[(nb * CHUNK + tid) * BATCH + bb];
        lds_x[cur ^ 1][tid] = xf;

#pragma unroll 1
        for (int s = 0; s < CHUNK; ++s) {
            // ---- layer 1: z = c1*y_n + ax_n = base + c1*svb_{n-1} ----
            float h1 = fast_tanh(fmaf(c1, svb, base));

            y += svb;                  // y_n (off critical path)

            // ---- layer 2 (quarter-K x 2 units): readlane broadcast +
            //      one pk-FMA per row covering both units ----
            f2 a0 = {0.f,0.f}, a1 = {0.f,0.f}, a2 = {0.f,0.f}, a3 = {0.f,0.f};
#define MACR(r) { \
            float h0_ = rdlane(h1, 4*(r)+0); f2 s0_ = { h0_, h0_ }; \
            a0 = __builtin_elementwise_fma(s0_, w##r##_0, a0); \
            float h1_ = rdlane(h1, 4*(r)+1); f2 s1_ = { h1_, h1_ }; \
            a1 = __builtin_elementwise_fma(s1_, w##r##_1, a1); \
            float h2_ = rdlane(h1, 4*(r)+2); f2 s2_ = { h2_, h2_ }; \
            a2 = __builtin_elementwise_fma(s2_, w##r##_2, a2); \
            float h3_ = rdlane(h1, 4*(r)+3); f2 s3_ = { h3_, h3_ }; \
            a3 = __builtin_elementwise_fma(s3_, w##r##_3, a3); }
            REP8(MACR)

            f2 pv = (a0 + a1) + (a2 + a3);   // {pA, pB} for this K-quarter

            // ---- publish partials ASAP ----
            const int buf = s & 1;           // parity double-buffer: WAR-safe
            lds_p[buf][w][l] = pv;           // ds_write_b64

            // ---- off-path work fills the pre-barrier drain window ----
            float xn  = (s < CHUNK - 1) ? lds_x[cur][s + 1] : lds_x[cur ^ 1][0];
            float axn = fmaf(w1x, xn, b1r);  // ax_{n+1}
            base = fmaf(c1, y, axn);         // c1*y_n + ax_{n+1}

            __syncthreads();                 // the ONE barrier per step

            // ---- finish: all 4 waves redundantly, bit-identical ----
            f2 r0 = lds_p[buf][0][l];
            f2 r1 = lds_p[buf][1][l];
            f2 r2 = lds_p[buf][2][l];
            f2 r3 = lds_p[buf][3][l];
            f2 q  = (r0 + r1) + (r2 + r3);   // {sum_jA, sum_jB} over K=128
            float h2A = fast_tanh(q.x + b2A);
            float h2B = fast_tanh(q.y + b2B);
            float p   = fmaf(h2A, w3A, h2B * w3B);

            // 64-lane DPP sum (covers all 128 units) -> lane 63
            asm volatile(
                "s_nop 1\n\t"
                "v_add_f32 %0, %0, %0 row_shr:1 bound_ctrl:0\n\t"
                "s_nop 1\n\t"
                "v_add_f32 %0, %0, %0 row_shr:2 bound_ctrl:0\n\t"
                "s_nop 1\n\t"
                "v_add_f32 %0, %0, %0 row_shr:4 bank_mask:0xe\n\t"
                "s_nop 1\n\t"
                "v_add_f32 %0, %0, %0 row_shr:8 bank_mask:0xc\n\t"
                "s_nop 1\n\t"
                "v_add_f32 %0, %0, %0 row_bcast:15 row_mask:0xa\n\t"
                "s_nop 1\n\t"
                "v_add_f32 %0, %0, %0 row_bcast:31 row_mask:0xc\n\t"
                : "+v"(p));
            float sv = rdlane(p, 63);        // compiler readlane (hazard-safe)

            svb = sv + b3s;                  // Δy_n; feeds next layer-1 directly
            ycap = (tid == s) ? (y + svb) : ycap;  // y_{n+1} capture (off-path)
        }
        out[(c * CHUNK + tid) * BATCH + bb] = ycap;   // 256 steps per store
        cur ^= 1;
    }
}

extern "C" void kernel_launch(void* const* d_in, const int* in_sizes, int n_in,
                              void* d_out, int out_size, void* d_ws, size_t ws_size,
                              hipStream_t stream) {
    const float* x  = (const float*)d_in[0];
    const float* W1 = (const float*)d_in[1];
    const float* b1 = (const float*)d_in[2];
    const float* W2 = (const float*)d_in[3];
    const float* b2 = (const float*)d_in[4];
    const float* W3 = (const float*)d_in[5];
    const float* b3 = (const float*)d_in[6];
    float* out = (float*)d_out;

    hipLaunchKernelGGL(ode_scan_kernel, dim3(BATCH), dim3(NTHR), 0, stream,
                       x, W1, b1, W2, b2, W3, b3, out);
}